// Round 16
// baseline (1417.653 us; speedup 1.0000x reference)
//
#include <hip/hip_runtime.h>

#define N_ROWS 32768
#define DIM 512
#define K_CODES 8192

// ---- i8 MFMA pass geometry: 128x256 tile, BKE=64 i8 elems (64 B/row),
// 8 waves (2M x 4N), acc[4][4], ring-2 dbuf (48 KB -> 3 blocks/CU, 24
// waves/CU), R5-verified 2-barrier step with counted vmcnt.
#define TMI 128
#define TNI 256
#define BKE 64               // K elements per step (i8)
#define NKTI (DIM / BKE)     // 8 K-steps
#define QSCALE 32.0f
#define SCL (2.0f / (QSCALE * QSCALE))   // dot -> -2*dot_true factor
#define EPS_I8 5.0f
#define QMARG 2.2f
#define SLOTS 64

// ---- fp32 fallback geometry
#define BN 64
#define BK 256
#define BD 32

typedef __attribute__((ext_vector_type(4))) float f32x4;
typedef __attribute__((ext_vector_type(4))) int i32x4;

#define AS1 __attribute__((address_space(1)))
#define AS3 __attribute__((address_space(3)))

__device__ inline unsigned int ord_f32(float f) {
    unsigned int u = __float_as_uint(f);
    return (u & 0x80000000u) ? ~u : (u | 0x80000000u);
}
__device__ inline float unord_f32(unsigned int u) {
    unsigned int b = (u & 0x80000000u) ? (u & 0x7fffffffu) : ~u;
    return __uint_as_float(b);
}
__device__ inline int q8(float f) {
    int t = __float2int_rn(f * QSCALE);
    t = t < -127 ? -127 : t;
    t = t > 127 ? 127 : t;
    return t & 255;
}
__device__ inline int pack4(float4 v) {
    return q8(v.x) | (q8(v.y) << 8) | (q8(v.z) << 16) | (q8(v.w) << 24);
}

// ---------------------------------------------------------------- e_sq only (fallback path)
__global__ __launch_bounds__(256) void esq_kernel(const float* __restrict__ embed,
                                                  float* __restrict__ e_sq) {
    int code = blockIdx.x * 4 + (threadIdx.x >> 6);
    int lane = threadIdx.x & 63;
    const float4* row = (const float4*)(embed + (size_t)code * DIM);
    float s = 0.f;
#pragma unroll
    for (int i = 0; i < 2; ++i) {
        float4 v = row[lane + i * 64];
        s += v.x * v.x + v.y * v.y + v.z * v.z + v.w * v.w;
    }
#pragma unroll
    for (int off = 32; off > 0; off >>= 1) s += __shfl_down(s, off);
    if (lane == 0) e_sq[code] = s;
}

// ---------------------------------------------------------------- fused embed -> i8 + e_sq (fp32)
__global__ __launch_bounds__(256) void cvt_embed_i8_kernel(const float* __restrict__ embed,
                                                           signed char* __restrict__ eq,
                                                           float* __restrict__ e_sq) {
    int code = blockIdx.x * 4 + (threadIdx.x >> 6);
    int lane = threadIdx.x & 63;
    const float4* row = (const float4*)(embed + (size_t)code * DIM);
    float4 v0 = row[lane * 2], v1 = row[lane * 2 + 1];
    float s = v0.x * v0.x + v0.y * v0.y + v0.z * v0.z + v0.w * v0.w
            + v1.x * v1.x + v1.y * v1.y + v1.z * v1.z + v1.w * v1.w;
    int2 o;
    o.x = pack4(v0);
    o.y = pack4(v1);
    *(int2*)(eq + (size_t)code * DIM + lane * 8) = o;
#pragma unroll
    for (int off = 32; off > 0; off >>= 1) s += __shfl_down(s, off);
    if (lane == 0) e_sq[code] = s;
}

// ---------------------------------------------------------------- x -> i8 (16 floats / thread)
__global__ __launch_bounds__(256) void cvt_x_i8_kernel(const float* __restrict__ in,
                                                       signed char* __restrict__ out, int n16) {
    int i = blockIdx.x * 256 + threadIdx.x;
    if (i >= n16) return;
    const float4* p = (const float4*)in + (size_t)i * 4;
    float4 v0 = p[0], v1 = p[1], v2 = p[2], v3 = p[3];
    int4 o;
    o.x = pack4(v0); o.y = pack4(v1); o.z = pack4(v2); o.w = pack4(v3);
    ((int4*)out)[i] = o;
}

// ---------------------------------------------------------------- pass A: i8, 128x256, 8 waves, RING-2, 3 blocks/CU, R5 2-barrier step
// Byte layout: 64 B/row, 16 B quarters. Quarter-swizzle (verified conflicts=0):
// chunk c stores global 16B-quarter (c&3)^((c>>3)&3) at linear LDS byte c*16;
// reader slot = l4 ^ ((l15>>1)&3).
// Step t (R5-verified): STAGE(buf^1, t+1) -> vmcnt(3) [t's stage landed,
// t+1's 3 loads in flight] -> barrier -> 8 ds_read_b128 + 16 i8 MFMA ->
// lgkm(0) -> barrier [reads of buf done before t+2 re-stages it].
// Ring-2 = 48 KB -> 3 blocks/CU (24 waves/CU): sequential step-rounds
// 8192*8/(3*256) = 85 vs R13's 128.
__global__ __launch_bounds__(512, 6) void passA_i8_kernel(const signed char* __restrict__ xq,
                                                          const signed char* __restrict__ eq,
                                                          const float* __restrict__ e_sq,
                                                          unsigned int* __restrict__ cand_count,
                                                          unsigned int* __restrict__ cands) {
    __shared__ __align__(16) signed char As[2][TMI * BKE];  // 2 x 8 KB
    __shared__ __align__(16) signed char Bs[2][TNI * BKE];  // 2 x 16 KB

    const int tid = threadIdx.x;
    const int lane = tid & 63;
    const int wv = tid >> 6;              // 8 waves: 2 (M) x 4 (N)
    const int wm = wv >> 2, wn = wv & 3;
    const int l15 = lane & 15, l4 = lane >> 4;
    const int slot = l4 ^ ((l15 >> 1) & 3);

    // XCD map: 8192 blocks = 8 xcd x (4 colblk x 256 rowblk); B/XCD = 0.5 MB
    const int bid = blockIdx.x;
    const int xcd = bid & 7, idx = bid >> 3;
    const int bx = xcd * 4 + (idx >> 8);   // code col-block 0..31
    const int by = idx & 255;              // row block 0..255
    const int row0 = by * TMI;
    const int col0 = bx * TNI;

    // staging chunks (16 B each): A = 512 (1/thread), B = 1024 (2/thread)
    const int cA = tid, cB0 = tid, cB1 = tid + 512;
    const int qA = ((cA & 3) ^ ((cA >> 3) & 3)) * 16;
    const int qB0 = ((cB0 & 3) ^ ((cB0 >> 3) & 3)) * 16;
    const int qB1 = ((cB1 & 3) ^ ((cB1 >> 3) & 3)) * 16;
    const signed char* xr = xq + (size_t)(row0 + (cA >> 2)) * DIM + qA;
    const signed char* er0 = eq + (size_t)(col0 + (cB0 >> 2)) * DIM + qB0;
    const signed char* er1 = eq + (size_t)(col0 + (cB1 >> 2)) * DIM + qB1;

    i32x4 acc[4][4];
#pragma unroll
    for (int m = 0; m < 4; ++m)
#pragma unroll
        for (int n = 0; n < 4; ++n) acc[m][n] = i32x4{0, 0, 0, 0};

#define STAGE(sl, kt)                                                                               \
    do {                                                                                            \
        __builtin_amdgcn_global_load_lds((const AS1 void*)(xr + (kt)),                              \
                                         (AS3 void*)&As[sl][cA * 16], 16, 0, 0);                    \
        __builtin_amdgcn_global_load_lds((const AS1 void*)(er0 + (kt)),                             \
                                         (AS3 void*)&Bs[sl][cB0 * 16], 16, 0, 0);                   \
        __builtin_amdgcn_global_load_lds((const AS1 void*)(er1 + (kt)),                             \
                                         (AS3 void*)&Bs[sl][cB1 * 16], 16, 0, 0);                   \
    } while (0)

    STAGE(0, 0);
    int buf = 0;
#pragma unroll
    for (int t = 0; t < NKTI; ++t) {
        if (t + 1 < NKTI) {
            STAGE(buf ^ 1, (t + 1) * BKE);
            asm volatile("s_waitcnt vmcnt(3)" ::: "memory");  // stage(t) landed; t+1 in flight
        } else {
            asm volatile("s_waitcnt vmcnt(0)" ::: "memory");
        }
        __builtin_amdgcn_s_barrier();
        i32x4 bfr[4], af[4];
#pragma unroll
        for (int n = 0; n < 4; ++n)
            bfr[n] = *(const i32x4*)&Bs[buf][(wn * 64 + n * 16 + l15) * BKE + slot * 16];
#pragma unroll
        for (int m = 0; m < 4; ++m)
            af[m] = *(const i32x4*)&As[buf][(wm * 64 + m * 16 + l15) * BKE + slot * 16];
        __builtin_amdgcn_s_setprio(1);
#pragma unroll
        for (int m = 0; m < 4; ++m)
#pragma unroll
            for (int n = 0; n < 4; ++n)
                acc[m][n] = __builtin_amdgcn_mfma_i32_16x16x64_i8(af[m], bfr[n], acc[m][n], 0, 0, 0);
        __builtin_amdgcn_s_setprio(0);
        asm volatile("s_waitcnt lgkmcnt(0)" ::: "memory");
        __builtin_amdgcn_sched_barrier(0);
        __builtin_amdgcn_s_barrier();     // reads of buf complete before t+2 re-stages it
        buf ^= 1;
    }
#undef STAGE

    // ---- epilogue (once per block). As is dead -> alias row_min.
    unsigned int* row_min = (unsigned int*)&As[0][0];

    float esr[4];
#pragma unroll
    for (int n = 0; n < 4; ++n) esr[n] = e_sq[col0 + wn * 64 + n * 16 + l15];

    if (tid < TMI) row_min[tid] = 0xFFFFFFFFu;
    __syncthreads();
    // convert i32 dots -> float scores in place: s = e_sq - 2*dot/QSCALE^2
#pragma unroll
    for (int m = 0; m < 4; ++m) {
        float rv[4];
#pragma unroll
        for (int r = 0; r < 4; ++r) rv[r] = 3.4e38f;
#pragma unroll
        for (int n = 0; n < 4; ++n)
#pragma unroll
            for (int r = 0; r < 4; ++r) {
                float s = fmaf(-SCL, (float)acc[m][n][r], esr[n]);
                acc[m][n][r] = __float_as_int(s);
                rv[r] = fminf(rv[r], s);
            }
#pragma unroll
        for (int d = 1; d < 16; d <<= 1)
#pragma unroll
            for (int r = 0; r < 4; ++r) rv[r] = fminf(rv[r], __shfl_xor(rv[r], d));
        if (l15 == 0) {
#pragma unroll
            for (int r = 0; r < 4; ++r)
                atomicMin(&row_min[wm * 64 + m * 16 + l4 * 4 + r], ord_f32(rv[r]));
        }
    }
    __syncthreads();
#pragma unroll
    for (int m = 0; m < 4; ++m)
#pragma unroll
        for (int r = 0; r < 4; ++r) {
            const int lrow = wm * 64 + m * 16 + l4 * 4 + r;
            const float th = unord_f32(row_min[lrow]) + EPS_I8;
            const int grow = row0 + lrow;
#pragma unroll
            for (int n = 0; n < 4; ++n) {
                float sv = __int_as_float(acc[m][n][r]);
                if (sv <= th) {
                    unsigned int s = atomicAdd(&cand_count[grow], 1u);
                    if (s < SLOTS) {
                        unsigned int code = (unsigned)(col0 + wn * 64 + n * 16 + l15);
                        cands[(size_t)grow * SLOTS + s] = (ord_f32(sv) & 0xFFFFE000u) | code;
                    }
                }
            }
        }
}

// ---------------------------------------------------------------- fp32 fallback pass A
__global__ __launch_bounds__(256) void passA_fp32_kernel(const float* __restrict__ x,
                                                         const float* __restrict__ embed,
                                                         const float* __restrict__ e_sq,
                                                         unsigned int* __restrict__ cand_count,
                                                         unsigned int* __restrict__ cands,
                                                         int slots) {
    __shared__ float xs[BD][BN];
    __shared__ float es[BD][BK];
    __shared__ float bbest[BN];
    __shared__ unsigned long long smin[BN][33];

    const int tid = threadIdx.x;
    const int tx = tid & 31, ty = tid >> 5;
    const int kb = blockIdx.x * BK;
    const int nb = blockIdx.y * BN;

    float acc[8][8];
#pragma unroll
    for (int i = 0; i < 8; ++i)
#pragma unroll
        for (int j = 0; j < 8; ++j) acc[i][j] = 0.f;

    for (int dt = 0; dt < DIM; dt += BD) {
        {
            int row = tid >> 2, seg = tid & 3;
            const float* xp = x + (size_t)(nb + row) * DIM + dt + seg * 4;
            float4 v0 = *(const float4*)(xp);
            float4 v1 = *(const float4*)(xp + 16);
            xs[seg * 4 + 0][row] = v0.x;  xs[seg * 4 + 1][row] = v0.y;
            xs[seg * 4 + 2][row] = v0.z;  xs[seg * 4 + 3][row] = v0.w;
            xs[seg * 4 + 16][row] = v1.x; xs[seg * 4 + 17][row] = v1.y;
            xs[seg * 4 + 18][row] = v1.z; xs[seg * 4 + 19][row] = v1.w;
        }
        {
            const float* ep = embed + (size_t)(kb + tid) * DIM + dt;
            float4 v[8];
#pragma unroll
            for (int i = 0; i < 8; ++i) v[i] = *(const float4*)(ep + i * 4);
#pragma unroll
            for (int i = 0; i < 8; ++i) {
                es[i * 4 + 0][tid] = v[i].x; es[i * 4 + 1][tid] = v[i].y;
                es[i * 4 + 2][tid] = v[i].z; es[i * 4 + 3][tid] = v[i].w;
            }
        }
        __syncthreads();
#pragma unroll
        for (int d = 0; d < BD; ++d) {
            float a[8], b[8];
            float4 a0 = *(const float4*)&xs[d][ty * 8];
            float4 a1 = *(const float4*)&xs[d][ty * 8 + 4];
            a[0] = a0.x; a[1] = a0.y; a[2] = a0.z; a[3] = a0.w;
            a[4] = a1.x; a[5] = a1.y; a[6] = a1.z; a[7] = a1.w;
#pragma unroll
            for (int j = 0; j < 8; ++j) b[j] = es[d][tx + j * 32];
#pragma unroll
            for (int i = 0; i < 8; ++i)
#pragma unroll
                for (int j = 0; j < 8; ++j) acc[i][j] = fmaf(a[i], b[j], acc[i][j]);
        }
        __syncthreads();
    }

    float esr[8];
#pragma unroll
    for (int j = 0; j < 8; ++j) esr[j] = e_sq[kb + tx + j * 32];
#pragma unroll
    for (int i = 0; i < 8; ++i) {
        float best = 3.4e38f;
#pragma unroll
        for (int j = 0; j < 8; ++j) {
            acc[i][j] = fmaf(-2.f, acc[i][j], esr[j]);
            if (acc[i][j] < best) best = acc[i][j];
        }
        smin[ty * 8 + i][tx] = ((unsigned long long)ord_f32(best) << 32);
    }
    __syncthreads();
    if (tid < BN) {
        unsigned long long m = smin[tid][0];
#pragma unroll 4
        for (int c = 1; c < 32; ++c) {
            unsigned long long v = smin[tid][c];
            if (v < m) m = v;
        }
        bbest[tid] = unord_f32((unsigned int)(m >> 32));
    }
    __syncthreads();
#pragma unroll
    for (int i = 0; i < 8; ++i) {
        int row = ty * 8 + i;
        float thr = bbest[row] + 1.5f;
#pragma unroll
        for (int j = 0; j < 8; ++j) {
            if (acc[i][j] <= thr) {
                unsigned int slot = atomicAdd(&cand_count[nb + row], 1u);
                if (slot < (unsigned)slots)
                    cands[(size_t)(nb + row) * slots + slot] =
                        (ord_f32(acc[i][j]) & 0xFFFFE000u) | (unsigned)(kb + tx + j * 32);
            }
        }
    }
}

// ---------------------------------------------------------------- pass B: key-filter + f64 survivor re-score + gather + STE + per-row loss partial
__global__ __launch_bounds__(256) void refine_kernel(const float* __restrict__ x,
                                                     const float* __restrict__ embed,
                                                     const unsigned int* __restrict__ cand_count,
                                                     const unsigned int* __restrict__ cands,
                                                     int slots,
                                                     float* __restrict__ out_q,
                                                     float* __restrict__ out_ind,
                                                     double* __restrict__ partials) {
    __shared__ double s_score[64];
    __shared__ unsigned int s_idx[64];
    __shared__ unsigned int s_minkey;
    __shared__ int s_ns;
    __shared__ int s_best;
    __shared__ float s_ls[4];

    const int row = blockIdx.x;
    const int tid = threadIdx.x;
    const int wave = tid >> 6, lane = tid & 63;
    const unsigned int craw = cand_count[row];
    const float4* xp = (const float4*)(x + (size_t)row * DIM);

    if (craw <= (unsigned)slots) {
        int c = (int)craw;
        if (c < 1) c = 1;
        if (tid < 64) {
            unsigned int k = (tid < c) ? cands[(size_t)row * slots + tid] : 0xFFFFFFFFu;
#pragma unroll
            for (int d = 1; d < 64; d <<= 1) {
                unsigned int o = (unsigned int)__shfl_xor((int)k, d);
                if (o < k) k = o;
            }
            if (tid == 0) { s_minkey = k; s_ns = 0; }
        }
        __syncthreads();
        const float th = unord_f32(s_minkey & 0xFFFFE000u) + EPS_I8 + QMARG;
        if (tid < c) {
            unsigned int k = cands[(size_t)row * slots + tid];
            if (unord_f32(k & 0xFFFFE000u) <= th) {
                int sl = atomicAdd(&s_ns, 1);
                s_idx[sl] = k & 0x1FFFu;
            }
        }
        __syncthreads();
        const int ns = s_ns;
        for (int ci = wave; ci < ns; ci += 4) {
            unsigned int k = s_idx[ci];
            const float4* ep = (const float4*)(embed + (size_t)k * DIM);
            double s = 0.0;
#pragma unroll
            for (int i = 0; i < 2; ++i) {
                float4 ev = ep[lane + i * 64];
                float4 xv = xp[lane + i * 64];
                s += (double)ev.x * ((double)ev.x - 2.0 * (double)xv.x);
                s += (double)ev.y * ((double)ev.y - 2.0 * (double)xv.y);
                s += (double)ev.z * ((double)ev.z - 2.0 * (double)xv.z);
                s += (double)ev.w * ((double)ev.w - 2.0 * (double)xv.w);
            }
#pragma unroll
            for (int off = 32; off > 0; off >>= 1) s += __shfl_down(s, off);
            if (lane == 0) s_score[ci] = s;
        }
        __syncthreads();
        if (tid == 0) {
            double best = s_score[0];
            unsigned int bidx = s_idx[0];
            for (int ci = 1; ci < ns; ++ci) {
                double sv = s_score[ci];
                unsigned int k = s_idx[ci];
                if (sv < best || (sv == best && k < bidx)) { best = sv; bidx = k; }
            }
            s_best = (int)bidx;
            out_ind[row] = (float)bidx;
        }
    } else {
        double wbest = 1e300;
        int wbidx = 0;
        for (int k = wave; k < K_CODES; k += 4) {
            const float4* ep = (const float4*)(embed + (size_t)k * DIM);
            double s = 0.0;
#pragma unroll
            for (int i = 0; i < 2; ++i) {
                float4 ev = ep[lane + i * 64];
                float4 xv = xp[lane + i * 64];
                s += (double)ev.x * ((double)ev.x - 2.0 * (double)xv.x);
                s += (double)ev.y * ((double)ev.y - 2.0 * (double)xv.y);
                s += (double)ev.z * ((double)ev.z - 2.0 * (double)xv.z);
                s += (double)ev.w * ((double)ev.w - 2.0 * (double)xv.w);
            }
#pragma unroll
            for (int off = 32; off > 0; off >>= 1) s += __shfl_down(s, off);
            if (lane == 0 && s < wbest) { wbest = s; wbidx = k; }
        }
        if (lane == 0) { s_score[wave] = wbest; s_idx[wave] = (unsigned)wbidx; }
        __syncthreads();
        if (tid == 0) {
            double best = s_score[0];
            unsigned int bidx = s_idx[0];
            for (int w = 1; w < 4; ++w) {
                if (s_score[w] < best || (s_score[w] == best && s_idx[w] < bidx)) {
                    best = s_score[w]; bidx = s_idx[w];
                }
            }
            s_best = (int)bidx;
            out_ind[row] = (float)bidx;
        }
    }
    __syncthreads();
    const int k = s_best;
    const float2* x2 = (const float2*)(x + (size_t)row * DIM);
    const float2* e2 = (const float2*)(embed + (size_t)k * DIM);
    float2* o2 = (float2*)(out_q + (size_t)row * DIM);
    float2 xv = x2[tid], ev = e2[tid];
    float2 o;
    o.x = xv.x + (ev.x - xv.x);
    o.y = xv.y + (ev.y - xv.y);
    o2[tid] = o;
    float dx = ev.x - xv.x, dy = ev.y - xv.y;
    float ls = dx * dx + dy * dy;
#pragma unroll
    for (int off = 32; off > 0; off >>= 1) ls += __shfl_down(ls, off);
    if (lane == 0) s_ls[wave] = ls;
    __syncthreads();
    if (tid == 0) partials[row] = (double)(s_ls[0] + s_ls[1] + s_ls[2] + s_ls[3]);
}

// ---------------------------------------------------------------- deterministic loss reduce
__global__ __launch_bounds__(1024) void finalize_kernel(const double* __restrict__ partials,
                                                        float* __restrict__ out_loss) {
    __shared__ double sm[1024];
    double s = 0.0;
    for (int i = threadIdx.x; i < N_ROWS; i += 1024) s += partials[i];
    sm[threadIdx.x] = s;
    __syncthreads();
    for (int off = 512; off > 0; off >>= 1) {
        if (threadIdx.x < off) sm[threadIdx.x] += sm[threadIdx.x + off];
        __syncthreads();
    }
    if (threadIdx.x == 0) *out_loss = (float)(sm[0] / ((double)N_ROWS * (double)DIM));
}

// ---------------------------------------------------------------- launch
extern "C" void kernel_launch(void* const* d_in, const int* in_sizes, int n_in,
                              void* d_out, int out_size, void* d_ws, size_t ws_size,
                              hipStream_t stream) {
    const float* x = (const float*)d_in[0];
    const float* embed = (const float*)d_in[1];
    float* out = (float*)d_out;
    float* out_q = out;
    float* out_ind = out + (size_t)N_ROWS * DIM;
    float* out_loss = out_ind + N_ROWS;

    char* ws = (char*)d_ws;
    float* e_sq = (float*)(ws + 16);                                   // 32 KB
    unsigned int* counts = (unsigned int*)(ws + 16 + 32768);           // 128 KB
    double* partials = (double*)(ws + 16 + 32768 + 131072);            // 256 KB
    char* dyn = ws + 16 + 32768 + 131072 + 262144;
    size_t fixed = (size_t)16 + 32768 + 131072 + 262144;
    size_t dyn_avail = ws_size > fixed ? ws_size - fixed : 0;

    const size_t xq_b = (size_t)N_ROWS * DIM;        // 16.8 MB
    const size_t eq_b = (size_t)K_CODES * DIM;       // 4.2 MB
    const size_t need_i8 = xq_b + eq_b + (size_t)N_ROWS * SLOTS * 4;

    hipMemsetAsync(counts, 0, (size_t)N_ROWS * 4, stream);

    if (dyn_avail >= need_i8) {
        signed char* xq = (signed char*)dyn;
        signed char* eq = (signed char*)(dyn + xq_b);
        unsigned int* cands = (unsigned int*)(dyn + xq_b + eq_b);
        cvt_embed_i8_kernel<<<K_CODES / 4, 256, 0, stream>>>(embed, eq, e_sq);
        cvt_x_i8_kernel<<<(N_ROWS * DIM / 16 + 255) / 256, 256, 0, stream>>>(x, xq, N_ROWS * DIM / 16);
        passA_i8_kernel<<<(K_CODES / TNI) * (N_ROWS / TMI), 512, 0, stream>>>(xq, eq, e_sq, counts, cands);
        refine_kernel<<<N_ROWS, 256, 0, stream>>>(x, embed, counts, cands, SLOTS, out_q, out_ind, partials);
    } else {
        esq_kernel<<<K_CODES / 4, 256, 0, stream>>>(embed, e_sq);
        unsigned int* cands = (unsigned int*)dyn;
        int slots = 40;
        size_t avail = dyn_avail / ((size_t)N_ROWS * 4);
        if (avail < (size_t)slots) slots = (int)avail;
        if (slots < 2) slots = 2;
        passA_fp32_kernel<<<dim3(K_CODES / BK, N_ROWS / BN), 256, 0, stream>>>(x, embed, e_sq, counts, cands, slots);
        refine_kernel<<<N_ROWS, 256, 0, stream>>>(x, embed, counts, cands, slots, out_q, out_ind, partials);
    }
    finalize_kernel<<<1, 1024, 0, stream>>>(partials, out_loss);
}

// Round 17
// 475.080 us; speedup vs baseline: 2.9840x; 2.9840x over previous
//
#include <hip/hip_runtime.h>

#define N_ROWS 32768
#define DIM 512
#define K_CODES 8192

// ---- i8 MFMA pass geometry: 128x256 tile, BKE=64 i8 elems (64 B/row),
// 8 waves (2M x 4N), acc[4][4], ring-3, launch_bounds(512,4) = 2 blocks/CU.
// MEASURED FEASIBLE CORNER (R13/R15: 401 us passA, 475 us total):
//  - R14 (256^2 tile @ same occupancy): acc=128 regs > 128-cap -> spill, 3.9x worse
//  - R16 (3 blocks/CU @ same tile): 85-reg cap < ~110 needed -> spill, 3.3x worse
//  - R6-R12 (7 schedule variants at bf16): all null vs simple counted-vmcnt ring
#define TMI 128
#define TNI 256
#define BKE 64               // K elements per step (i8)
#define NKTI (DIM / BKE)     // 8 K-steps
#define QSCALE 32.0f
#define SCL (2.0f / (QSCALE * QSCALE))   // dot -> -2*dot_true factor
#define EPS_I8 5.0f
#define QMARG 2.2f
#define SLOTS 64

// ---- fp32 fallback geometry
#define BN 64
#define BK 256
#define BD 32

typedef __attribute__((ext_vector_type(4))) float f32x4;
typedef __attribute__((ext_vector_type(4))) int i32x4;

#define AS1 __attribute__((address_space(1)))
#define AS3 __attribute__((address_space(3)))

__device__ inline unsigned int ord_f32(float f) {
    unsigned int u = __float_as_uint(f);
    return (u & 0x80000000u) ? ~u : (u | 0x80000000u);
}
__device__ inline float unord_f32(unsigned int u) {
    unsigned int b = (u & 0x80000000u) ? (u & 0x7fffffffu) : ~u;
    return __uint_as_float(b);
}
__device__ inline int q8(float f) {
    int t = __float2int_rn(f * QSCALE);
    t = t < -127 ? -127 : t;
    t = t > 127 ? 127 : t;
    return t & 255;
}
__device__ inline int pack4(float4 v) {
    return q8(v.x) | (q8(v.y) << 8) | (q8(v.z) << 16) | (q8(v.w) << 24);
}

// ---------------------------------------------------------------- e_sq only (fallback path)
__global__ __launch_bounds__(256) void esq_kernel(const float* __restrict__ embed,
                                                  float* __restrict__ e_sq) {
    int code = blockIdx.x * 4 + (threadIdx.x >> 6);
    int lane = threadIdx.x & 63;
    const float4* row = (const float4*)(embed + (size_t)code * DIM);
    float s = 0.f;
#pragma unroll
    for (int i = 0; i < 2; ++i) {
        float4 v = row[lane + i * 64];
        s += v.x * v.x + v.y * v.y + v.z * v.z + v.w * v.w;
    }
#pragma unroll
    for (int off = 32; off > 0; off >>= 1) s += __shfl_down(s, off);
    if (lane == 0) e_sq[code] = s;
}

// ---------------------------------------------------------------- fused embed -> i8 + e_sq (fp32)
__global__ __launch_bounds__(256) void cvt_embed_i8_kernel(const float* __restrict__ embed,
                                                           signed char* __restrict__ eq,
                                                           float* __restrict__ e_sq) {
    int code = blockIdx.x * 4 + (threadIdx.x >> 6);
    int lane = threadIdx.x & 63;
    const float4* row = (const float4*)(embed + (size_t)code * DIM);
    float4 v0 = row[lane * 2], v1 = row[lane * 2 + 1];
    float s = v0.x * v0.x + v0.y * v0.y + v0.z * v0.z + v0.w * v0.w
            + v1.x * v1.x + v1.y * v1.y + v1.z * v1.z + v1.w * v1.w;
    int2 o;
    o.x = pack4(v0);
    o.y = pack4(v1);
    *(int2*)(eq + (size_t)code * DIM + lane * 8) = o;
#pragma unroll
    for (int off = 32; off > 0; off >>= 1) s += __shfl_down(s, off);
    if (lane == 0) e_sq[code] = s;
}

// ---------------------------------------------------------------- x -> i8 (16 floats / thread)
__global__ __launch_bounds__(256) void cvt_x_i8_kernel(const float* __restrict__ in,
                                                       signed char* __restrict__ out, int n16) {
    int i = blockIdx.x * 256 + threadIdx.x;
    if (i >= n16) return;
    const float4* p = (const float4*)in + (size_t)i * 4;
    float4 v0 = p[0], v1 = p[1], v2 = p[2], v3 = p[3];
    int4 o;
    o.x = pack4(v0); o.y = pack4(v1); o.z = pack4(v2); o.w = pack4(v3);
    ((int4*)out)[i] = o;
}

// ---------------------------------------------------------------- pass A: i8, 128x256, 8 waves, ring-3, counted vmcnt (R13/R15 proven)
// Byte layout: 64 B/row, 16 B quarters. Quarter-swizzle (verified conflicts=0):
// chunk c stores global 16B-quarter (c&3)^((c>>3)&3) at linear LDS byte c*16;
// reader slot = l4 ^ ((l15>>1)&3).
// Step t: vmcnt(3) -> barrier -> STAGE(t+2) -> 12 ds_read_b128 + 16 i8 MFMA
// (no manual lgkm pin; compiler interleaves).
__global__ __launch_bounds__(512, 4) void passA_i8_kernel(const signed char* __restrict__ xq,
                                                          const signed char* __restrict__ eq,
                                                          const float* __restrict__ e_sq,
                                                          unsigned int* __restrict__ cand_count,
                                                          unsigned int* __restrict__ cands) {
    __shared__ __align__(16) signed char As[3][TMI * BKE];  // 3 x 8 KB
    __shared__ __align__(16) signed char Bs[3][TNI * BKE];  // 3 x 16 KB

    const int tid = threadIdx.x;
    const int lane = tid & 63;
    const int wv = tid >> 6;              // 8 waves: 2 (M) x 4 (N)
    const int wm = wv >> 2, wn = wv & 3;
    const int l15 = lane & 15, l4 = lane >> 4;
    const int slot = l4 ^ ((l15 >> 1) & 3);

    // XCD map: 8192 blocks = 8 xcd x (4 colblk x 256 rowblk); B/XCD = 0.5 MB
    const int bid = blockIdx.x;
    const int xcd = bid & 7, idx = bid >> 3;
    const int bx = xcd * 4 + (idx >> 8);   // code col-block 0..31
    const int by = idx & 255;              // row block 0..255
    const int row0 = by * TMI;
    const int col0 = bx * TNI;

    // staging chunks (16 B each): A = 512 (1/thread), B = 1024 (2/thread)
    const int cA = tid, cB0 = tid, cB1 = tid + 512;
    const int qA = ((cA & 3) ^ ((cA >> 3) & 3)) * 16;
    const int qB0 = ((cB0 & 3) ^ ((cB0 >> 3) & 3)) * 16;
    const int qB1 = ((cB1 & 3) ^ ((cB1 >> 3) & 3)) * 16;
    const signed char* xr = xq + (size_t)(row0 + (cA >> 2)) * DIM + qA;
    const signed char* er0 = eq + (size_t)(col0 + (cB0 >> 2)) * DIM + qB0;
    const signed char* er1 = eq + (size_t)(col0 + (cB1 >> 2)) * DIM + qB1;

    i32x4 acc[4][4];
#pragma unroll
    for (int m = 0; m < 4; ++m)
#pragma unroll
        for (int n = 0; n < 4; ++n) acc[m][n] = i32x4{0, 0, 0, 0};

#define STAGE(sl, kt)                                                                               \
    do {                                                                                            \
        __builtin_amdgcn_global_load_lds((const AS1 void*)(xr + (kt)),                              \
                                         (AS3 void*)&As[sl][cA * 16], 16, 0, 0);                    \
        __builtin_amdgcn_global_load_lds((const AS1 void*)(er0 + (kt)),                             \
                                         (AS3 void*)&Bs[sl][cB0 * 16], 16, 0, 0);                   \
        __builtin_amdgcn_global_load_lds((const AS1 void*)(er1 + (kt)),                             \
                                         (AS3 void*)&Bs[sl][cB1 * 16], 16, 0, 0);                   \
    } while (0)

    STAGE(0, 0);
    STAGE(1, BKE);
#pragma unroll
    for (int t = 0; t < NKTI; ++t) {
        if (t + 1 < NKTI) {
            asm volatile("s_waitcnt vmcnt(3)" ::: "memory");  // stage(t) landed; t+1 in flight
        } else {
            asm volatile("s_waitcnt vmcnt(0)" ::: "memory");
        }
        __builtin_amdgcn_s_barrier();
        if (t + 2 < NKTI) STAGE((t + 2) % 3, (t + 2) * BKE);  // after barrier: race-free
        const int buf = t % 3;
        i32x4 bfr[4], af[4];
#pragma unroll
        for (int n = 0; n < 4; ++n)
            bfr[n] = *(const i32x4*)&Bs[buf][(wn * 64 + n * 16 + l15) * BKE + slot * 16];
#pragma unroll
        for (int m = 0; m < 4; ++m)
            af[m] = *(const i32x4*)&As[buf][(wm * 64 + m * 16 + l15) * BKE + slot * 16];
        __builtin_amdgcn_s_setprio(1);
#pragma unroll
        for (int m = 0; m < 4; ++m)
#pragma unroll
            for (int n = 0; n < 4; ++n)
                acc[m][n] = __builtin_amdgcn_mfma_i32_16x16x64_i8(af[m], bfr[n], acc[m][n], 0, 0, 0);
        __builtin_amdgcn_s_setprio(0);
    }
#undef STAGE

    // ---- epilogue (once per block). As is dead -> alias row_min.
    unsigned int* row_min = (unsigned int*)&As[0][0];

    float esr[4];
#pragma unroll
    for (int n = 0; n < 4; ++n) esr[n] = e_sq[col0 + wn * 64 + n * 16 + l15];

    __syncthreads();                      // all MFMA/ds done; safe to alias As
    if (tid < TMI) row_min[tid] = 0xFFFFFFFFu;
    __syncthreads();
    // convert i32 dots -> float scores in place: s = e_sq - 2*dot/QSCALE^2
#pragma unroll
    for (int m = 0; m < 4; ++m) {
        float rv[4];
#pragma unroll
        for (int r = 0; r < 4; ++r) rv[r] = 3.4e38f;
#pragma unroll
        for (int n = 0; n < 4; ++n)
#pragma unroll
            for (int r = 0; r < 4; ++r) {
                float s = fmaf(-SCL, (float)acc[m][n][r], esr[n]);
                acc[m][n][r] = __float_as_int(s);
                rv[r] = fminf(rv[r], s);
            }
#pragma unroll
        for (int d = 1; d < 16; d <<= 1)
#pragma unroll
            for (int r = 0; r < 4; ++r) rv[r] = fminf(rv[r], __shfl_xor(rv[r], d));
        if (l15 == 0) {
#pragma unroll
            for (int r = 0; r < 4; ++r)
                atomicMin(&row_min[wm * 64 + m * 16 + l4 * 4 + r], ord_f32(rv[r]));
        }
    }
    __syncthreads();
#pragma unroll
    for (int m = 0; m < 4; ++m)
#pragma unroll
        for (int r = 0; r < 4; ++r) {
            const int lrow = wm * 64 + m * 16 + l4 * 4 + r;
            const float th = unord_f32(row_min[lrow]) + EPS_I8;
            const int grow = row0 + lrow;
#pragma unroll
            for (int n = 0; n < 4; ++n) {
                float sv = __int_as_float(acc[m][n][r]);
                if (sv <= th) {
                    unsigned int s = atomicAdd(&cand_count[grow], 1u);
                    if (s < SLOTS) {
                        unsigned int code = (unsigned)(col0 + wn * 64 + n * 16 + l15);
                        cands[(size_t)grow * SLOTS + s] = (ord_f32(sv) & 0xFFFFE000u) | code;
                    }
                }
            }
        }
}

// ---------------------------------------------------------------- fp32 fallback pass A
__global__ __launch_bounds__(256) void passA_fp32_kernel(const float* __restrict__ x,
                                                         const float* __restrict__ embed,
                                                         const float* __restrict__ e_sq,
                                                         unsigned int* __restrict__ cand_count,
                                                         unsigned int* __restrict__ cands,
                                                         int slots) {
    __shared__ float xs[BD][BN];
    __shared__ float es[BD][BK];
    __shared__ float bbest[BN];
    __shared__ unsigned long long smin[BN][33];

    const int tid = threadIdx.x;
    const int tx = tid & 31, ty = tid >> 5;
    const int kb = blockIdx.x * BK;
    const int nb = blockIdx.y * BN;

    float acc[8][8];
#pragma unroll
    for (int i = 0; i < 8; ++i)
#pragma unroll
        for (int j = 0; j < 8; ++j) acc[i][j] = 0.f;

    for (int dt = 0; dt < DIM; dt += BD) {
        {
            int row = tid >> 2, seg = tid & 3;
            const float* xp = x + (size_t)(nb + row) * DIM + dt + seg * 4;
            float4 v0 = *(const float4*)(xp);
            float4 v1 = *(const float4*)(xp + 16);
            xs[seg * 4 + 0][row] = v0.x;  xs[seg * 4 + 1][row] = v0.y;
            xs[seg * 4 + 2][row] = v0.z;  xs[seg * 4 + 3][row] = v0.w;
            xs[seg * 4 + 16][row] = v1.x; xs[seg * 4 + 17][row] = v1.y;
            xs[seg * 4 + 18][row] = v1.z; xs[seg * 4 + 19][row] = v1.w;
        }
        {
            const float* ep = embed + (size_t)(kb + tid) * DIM + dt;
            float4 v[8];
#pragma unroll
            for (int i = 0; i < 8; ++i) v[i] = *(const float4*)(ep + i * 4);
#pragma unroll
            for (int i = 0; i < 8; ++i) {
                es[i * 4 + 0][tid] = v[i].x; es[i * 4 + 1][tid] = v[i].y;
                es[i * 4 + 2][tid] = v[i].z; es[i * 4 + 3][tid] = v[i].w;
            }
        }
        __syncthreads();
#pragma unroll
        for (int d = 0; d < BD; ++d) {
            float a[8], b[8];
            float4 a0 = *(const float4*)&xs[d][ty * 8];
            float4 a1 = *(const float4*)&xs[d][ty * 8 + 4];
            a[0] = a0.x; a[1] = a0.y; a[2] = a0.z; a[3] = a0.w;
            a[4] = a1.x; a[5] = a1.y; a[6] = a1.z; a[7] = a1.w;
#pragma unroll
            for (int j = 0; j < 8; ++j) b[j] = es[d][tx + j * 32];
#pragma unroll
            for (int i = 0; i < 8; ++i)
#pragma unroll
                for (int j = 0; j < 8; ++j) acc[i][j] = fmaf(a[i], b[j], acc[i][j]);
        }
        __syncthreads();
    }

    float esr[8];
#pragma unroll
    for (int j = 0; j < 8; ++j) esr[j] = e_sq[kb + tx + j * 32];
#pragma unroll
    for (int i = 0; i < 8; ++i) {
        float best = 3.4e38f;
#pragma unroll
        for (int j = 0; j < 8; ++j) {
            acc[i][j] = fmaf(-2.f, acc[i][j], esr[j]);
            if (acc[i][j] < best) best = acc[i][j];
        }
        smin[ty * 8 + i][tx] = ((unsigned long long)ord_f32(best) << 32);
    }
    __syncthreads();
    if (tid < BN) {
        unsigned long long m = smin[tid][0];
#pragma unroll 4
        for (int c = 1; c < 32; ++c) {
            unsigned long long v = smin[tid][c];
            if (v < m) m = v;
        }
        bbest[tid] = unord_f32((unsigned int)(m >> 32));
    }
    __syncthreads();
#pragma unroll
    for (int i = 0; i < 8; ++i) {
        int row = ty * 8 + i;
        float thr = bbest[row] + 1.5f;
#pragma unroll
        for (int j = 0; j < 8; ++j) {
            if (acc[i][j] <= thr) {
                unsigned int slot = atomicAdd(&cand_count[nb + row], 1u);
                if (slot < (unsigned)slots)
                    cands[(size_t)(nb + row) * slots + slot] =
                        (ord_f32(acc[i][j]) & 0xFFFFE000u) | (unsigned)(kb + tx + j * 32);
            }
        }
    }
}

// ---------------------------------------------------------------- pass B: key-filter + f64 survivor re-score + gather + STE + per-row loss partial
__global__ __launch_bounds__(256) void refine_kernel(const float* __restrict__ x,
                                                     const float* __restrict__ embed,
                                                     const unsigned int* __restrict__ cand_count,
                                                     const unsigned int* __restrict__ cands,
                                                     int slots,
                                                     float* __restrict__ out_q,
                                                     float* __restrict__ out_ind,
                                                     double* __restrict__ partials) {
    __shared__ double s_score[64];
    __shared__ unsigned int s_idx[64];
    __shared__ unsigned int s_minkey;
    __shared__ int s_ns;
    __shared__ int s_best;
    __shared__ float s_ls[4];

    const int row = blockIdx.x;
    const int tid = threadIdx.x;
    const int wave = tid >> 6, lane = tid & 63;
    const unsigned int craw = cand_count[row];
    const float4* xp = (const float4*)(x + (size_t)row * DIM);

    if (craw <= (unsigned)slots) {
        int c = (int)craw;
        if (c < 1) c = 1;
        if (tid < 64) {
            unsigned int k = (tid < c) ? cands[(size_t)row * slots + tid] : 0xFFFFFFFFu;
#pragma unroll
            for (int d = 1; d < 64; d <<= 1) {
                unsigned int o = (unsigned int)__shfl_xor((int)k, d);
                if (o < k) k = o;
            }
            if (tid == 0) { s_minkey = k; s_ns = 0; }
        }
        __syncthreads();
        const float th = unord_f32(s_minkey & 0xFFFFE000u) + EPS_I8 + QMARG;
        if (tid < c) {
            unsigned int k = cands[(size_t)row * slots + tid];
            if (unord_f32(k & 0xFFFFE000u) <= th) {
                int sl = atomicAdd(&s_ns, 1);
                s_idx[sl] = k & 0x1FFFu;
            }
        }
        __syncthreads();
        const int ns = s_ns;
        for (int ci = wave; ci < ns; ci += 4) {
            unsigned int k = s_idx[ci];
            const float4* ep = (const float4*)(embed + (size_t)k * DIM);
            double s = 0.0;
#pragma unroll
            for (int i = 0; i < 2; ++i) {
                float4 ev = ep[lane + i * 64];
                float4 xv = xp[lane + i * 64];
                s += (double)ev.x * ((double)ev.x - 2.0 * (double)xv.x);
                s += (double)ev.y * ((double)ev.y - 2.0 * (double)xv.y);
                s += (double)ev.z * ((double)ev.z - 2.0 * (double)xv.z);
                s += (double)ev.w * ((double)ev.w - 2.0 * (double)xv.w);
            }
#pragma unroll
            for (int off = 32; off > 0; off >>= 1) s += __shfl_down(s, off);
            if (lane == 0) s_score[ci] = s;
        }
        __syncthreads();
        if (tid == 0) {
            double best = s_score[0];
            unsigned int bidx = s_idx[0];
            for (int ci = 1; ci < ns; ++ci) {
                double sv = s_score[ci];
                unsigned int k = s_idx[ci];
                if (sv < best || (sv == best && k < bidx)) { best = sv; bidx = k; }
            }
            s_best = (int)bidx;
            out_ind[row] = (float)bidx;
        }
    } else {
        double wbest = 1e300;
        int wbidx = 0;
        for (int k = wave; k < K_CODES; k += 4) {
            const float4* ep = (const float4*)(embed + (size_t)k * DIM);
            double s = 0.0;
#pragma unroll
            for (int i = 0; i < 2; ++i) {
                float4 ev = ep[lane + i * 64];
                float4 xv = xp[lane + i * 64];
                s += (double)ev.x * ((double)ev.x - 2.0 * (double)xv.x);
                s += (double)ev.y * ((double)ev.y - 2.0 * (double)xv.y);
                s += (double)ev.z * ((double)ev.z - 2.0 * (double)xv.z);
                s += (double)ev.w * ((double)ev.w - 2.0 * (double)xv.w);
            }
#pragma unroll
            for (int off = 32; off > 0; off >>= 1) s += __shfl_down(s, off);
            if (lane == 0 && s < wbest) { wbest = s; wbidx = k; }
        }
        if (lane == 0) { s_score[wave] = wbest; s_idx[wave] = (unsigned)wbidx; }
        __syncthreads();
        if (tid == 0) {
            double best = s_score[0];
            unsigned int bidx = s_idx[0];
            for (int w = 1; w < 4; ++w) {
                if (s_score[w] < best || (s_score[w] == best && s_idx[w] < bidx)) {
                    best = s_score[w]; bidx = s_idx[w];
                }
            }
            s_best = (int)bidx;
            out_ind[row] = (float)bidx;
        }
    }
    __syncthreads();
    const int k = s_best;
    const float2* x2 = (const float2*)(x + (size_t)row * DIM);
    const float2* e2 = (const float2*)(embed + (size_t)k * DIM);
    float2* o2 = (float2*)(out_q + (size_t)row * DIM);
    float2 xv = x2[tid], ev = e2[tid];
    float2 o;
    o.x = xv.x + (ev.x - xv.x);
    o.y = xv.y + (ev.y - xv.y);
    o2[tid] = o;
    float dx = ev.x - xv.x, dy = ev.y - xv.y;
    float ls = dx * dx + dy * dy;
#pragma unroll
    for (int off = 32; off > 0; off >>= 1) ls += __shfl_down(ls, off);
    if (lane == 0) s_ls[wave] = ls;
    __syncthreads();
    if (tid == 0) partials[row] = (double)(s_ls[0] + s_ls[1] + s_ls[2] + s_ls[3]);
}

// ---------------------------------------------------------------- deterministic loss reduce
__global__ __launch_bounds__(1024) void finalize_kernel(const double* __restrict__ partials,
                                                        float* __restrict__ out_loss) {
    __shared__ double sm[1024];
    double s = 0.0;
    for (int i = threadIdx.x; i < N_ROWS; i += 1024) s += partials[i];
    sm[threadIdx.x] = s;
    __syncthreads();
    for (int off = 512; off > 0; off >>= 1) {
        if (threadIdx.x < off) sm[threadIdx.x] += sm[threadIdx.x + off];
        __syncthreads();
    }
    if (threadIdx.x == 0) *out_loss = (float)(sm[0] / ((double)N_ROWS * (double)DIM));
}

// ---------------------------------------------------------------- launch
extern "C" void kernel_launch(void* const* d_in, const int* in_sizes, int n_in,
                              void* d_out, int out_size, void* d_ws, size_t ws_size,
                              hipStream_t stream) {
    const float* x = (const float*)d_in[0];
    const float* embed = (const float*)d_in[1];
    float* out = (float*)d_out;
    float* out_q = out;
    float* out_ind = out + (size_t)N_ROWS * DIM;
    float* out_loss = out_ind + N_ROWS;

    char* ws = (char*)d_ws;
    float* e_sq = (float*)(ws + 16);                                   // 32 KB
    unsigned int* counts = (unsigned int*)(ws + 16 + 32768);           // 128 KB
    double* partials = (double*)(ws + 16 + 32768 + 131072);            // 256 KB
    char* dyn = ws + 16 + 32768 + 131072 + 262144;
    size_t fixed = (size_t)16 + 32768 + 131072 + 262144;
    size_t dyn_avail = ws_size > fixed ? ws_size - fixed : 0;

    const size_t xq_b = (size_t)N_ROWS * DIM;        // 16.8 MB
    const size_t eq_b = (size_t)K_CODES * DIM;       // 4.2 MB
    const size_t need_i8 = xq_b + eq_b + (size_t)N_ROWS * SLOTS * 4;

    hipMemsetAsync(counts, 0, (size_t)N_ROWS * 4, stream);

    if (dyn_avail >= need_i8) {
        signed char* xq = (signed char*)dyn;
        signed char* eq = (signed char*)(dyn + xq_b);
        unsigned int* cands = (unsigned int*)(dyn + xq_b + eq_b);
        cvt_embed_i8_kernel<<<K_CODES / 4, 256, 0, stream>>>(embed, eq, e_sq);
        cvt_x_i8_kernel<<<(N_ROWS * DIM / 16 + 255) / 256, 256, 0, stream>>>(x, xq, N_ROWS * DIM / 16);
        passA_i8_kernel<<<(K_CODES / TNI) * (N_ROWS / TMI), 512, 0, stream>>>(xq, eq, e_sq, counts, cands);
        refine_kernel<<<N_ROWS, 256, 0, stream>>>(x, embed, counts, cands, SLOTS, out_q, out_ind, partials);
    } else {
        esq_kernel<<<K_CODES / 4, 256, 0, stream>>>(embed, e_sq);
        unsigned int* cands = (unsigned int*)dyn;
        int slots = 40;
        size_t avail = dyn_avail / ((size_t)N_ROWS * 4);
        if (avail < (size_t)slots) slots = (int)avail;
        if (slots < 2) slots = 2;
        passA_fp32_kernel<<<dim3(K_CODES / BK, N_ROWS / BN), 256, 0, stream>>>(x, embed, e_sq, counts, cands, slots);
        refine_kernel<<<N_ROWS, 256, 0, stream>>>(x, embed, counts, cands, slots, out_q, out_ind, partials);
    }
    finalize_kernel<<<1, 1024, 0, stream>>>(partials, out_loss);
}